// Round 1
// baseline (376.527 us; speedup 1.0000x reference)
//
#include <hip/hip_runtime.h>

// Problem constants (from reference): B=4, N=128, M=128, D=256, BD=1024
#define DD   256
#define BD   1024
#define NB   4
#define NN   128
#define MM   128

// ---------------------------------------------------------------------------
// Kernel 1: Aw[d,e] = sum_k A[d,e,k] * W[k]
// A is (D, D, BD) with k contiguous -> each (d,e) row is 4 KB contiguous.
// One wave per row: 64 lanes x 4 float4 = 1024 floats. W staged in LDS.
// Grid: 65536 rows / 4 waves-per-block = 16384 blocks x 256 threads.
// ---------------------------------------------------------------------------
__global__ __launch_bounds__(256) void reduce_A_kernel(
    const float* __restrict__ A, const float* __restrict__ W,
    float* __restrict__ Aw)
{
    __shared__ float wsh[BD];
    const int t = threadIdx.x;
#pragma unroll
    for (int i = 0; i < 4; ++i) wsh[t + i * 256] = W[t + i * 256];
    __syncthreads();

    const int lane = t & 63;
    const int wave = t >> 6;
    const long long row = (long long)blockIdx.x * 4 + wave;  // < 65536

    const float4* __restrict__ Arow = (const float4*)(A + row * BD);
    const float4* __restrict__ W4   = (const float4*)wsh;

    float acc = 0.f;
#pragma unroll
    for (int q = 0; q < 4; ++q) {
        float4 a = Arow[q * 64 + lane];
        float4 w = W4[q * 64 + lane];
        acc += a.x * w.x + a.y * w.y + a.z * w.z + a.w * w.w;
    }
#pragma unroll
    for (int off = 32; off > 0; off >>= 1)
        acc += __shfl_down(acc, off, 64);
    if (lane == 0) Aw[row] = acc;
}

// ---------------------------------------------------------------------------
// Kernel 2: per (b,n): Z[e] = sum_d X[b,n,d]*Aw[d,e]; S[b,n,m] = sum_e Z[e]*Y[b,m,e] + bias
// One block of 256 per (b,n). Phase 1: e = tid, coalesced Aw reads, X row in LDS.
// Phase 2: 256 threads cover 128 outputs x 2 e-halves, combine via LDS.
// ---------------------------------------------------------------------------
__global__ __launch_bounds__(256) void bilinear_fused_kernel(
    const float* __restrict__ X, const float* __restrict__ Y,
    const float* __restrict__ Aw, const float* __restrict__ bias,
    float* __restrict__ S)
{
    const int bn = blockIdx.x;        // b*128 + n
    const int b  = bn >> 7;
    const int t  = threadIdx.x;

    __shared__ float xrow[DD];
    __shared__ float zrow[DD];
    __shared__ float partial[256];

    xrow[t] = X[(long long)bn * DD + t];
    __syncthreads();

    // Phase 1: Z[t] = sum_d xrow[d] * Aw[d*256 + t]
    float acc = 0.f;
#pragma unroll 8
    for (int d = 0; d < DD; ++d) {
        acc += xrow[d] * Aw[d * DD + t];
    }
    zrow[t] = acc;
    __syncthreads();

    // Phase 2: outputs m = t&127, e-half = t>>7
    const int m  = t & 127;
    const int eh = (t >> 7) << 7;  // 0 or 128
    const float4* __restrict__ Y4 = (const float4*)(Y + ((long long)b * MM + m) * DD + eh);
    const float4* __restrict__ Z4 = (const float4*)(zrow + eh);

    float s = 0.f;
#pragma unroll 8
    for (int e = 0; e < 32; ++e) {
        float4 y = Y4[e];
        float4 z = Z4[e];
        s += z.x * y.x + z.y * y.y + z.z * y.z + z.w * y.w;
    }
    partial[t] = s;
    __syncthreads();

    if (t < 128) {
        S[(long long)bn * MM + t] = partial[t] + partial[t + 128] + bias[0];
    }
}

extern "C" void kernel_launch(void* const* d_in, const int* in_sizes, int n_in,
                              void* d_out, int out_size, void* d_ws, size_t ws_size,
                              hipStream_t stream) {
    const float* X    = (const float*)d_in[0];  // [4,128,256]
    const float* Y    = (const float*)d_in[1];  // [4,128,256]
    const float* A    = (const float*)d_in[2];  // [256,256,1024]
    const float* W    = (const float*)d_in[3];  // [1,1024]
    const float* bias = (const float*)d_in[4];  // [1]
    float* S  = (float*)d_out;                  // [4,128,128]
    float* Aw = (float*)d_ws;                   // 65536 floats = 256 KB scratch

    // Kernel 1: 65536 rows, 4 waves/block
    reduce_A_kernel<<<dim3(65536 / 4), dim3(256), 0, stream>>>(A, W, Aw);

    // Kernel 2: one block per (b, n)
    bilinear_fused_kernel<<<dim3(NB * NN), dim3(256), 0, stream>>>(X, Y, Aw, bias, S);
}

// Round 3
// 361.844 us; speedup vs baseline: 1.0406x; 1.0406x over previous
//
#include <hip/hip_runtime.h>

// Problem constants (from reference): B=4, N=128, M=128, D=256, BD=1024
#define DD   256
#define BD   1024
#define NB   4
#define NN   128
#define MM   128

// Native vector type — __builtin_nontemporal_load requires a native vector,
// not HIP's float4 class type.
typedef float vfloat4 __attribute__((ext_vector_type(4)));

// ---------------------------------------------------------------------------
// Kernel 1: Aw[d,e] = sum_k A[d,e,k] * W[k]
// A is (D, D, BD), k contiguous -> each (d,e) row is 4 KB contiguous.
// One wave per 4 rows, W held in 16 registers/lane (no LDS, no syncthreads).
// 16 nontemporal float4 loads in flight per thread. Coalesced float4 store.
// Grid: 65536 rows / (4 waves * 4 rows) = 4096 blocks x 256 threads.
// ---------------------------------------------------------------------------
__global__ __launch_bounds__(256) void reduce_A_kernel(
    const float* __restrict__ A, const float* __restrict__ W,
    float* __restrict__ Aw)
{
    const int t    = threadIdx.x;
    const int lane = t & 63;
    const int wid  = t >> 6;
    const int row0 = blockIdx.x * 16 + wid * 4;   // first of 4 rows for this wave

    const vfloat4* __restrict__ W4 = (const vfloat4*)W;
    const vfloat4 w0 = W4[lane];
    const vfloat4 w1 = W4[lane + 64];
    const vfloat4 w2 = W4[lane + 128];
    const vfloat4 w3 = W4[lane + 192];

    const vfloat4* __restrict__ p = (const vfloat4*)(A + (size_t)row0 * BD) + lane;

    float acc[4];
#pragma unroll
    for (int r = 0; r < 4; ++r) {
        const vfloat4* __restrict__ pr = p + r * 256;
        vfloat4 a0 = __builtin_nontemporal_load(pr);
        vfloat4 a1 = __builtin_nontemporal_load(pr + 64);
        vfloat4 a2 = __builtin_nontemporal_load(pr + 128);
        vfloat4 a3 = __builtin_nontemporal_load(pr + 192);
        acc[r] = a0.x * w0.x + a0.y * w0.y + a0.z * w0.z + a0.w * w0.w
               + a1.x * w1.x + a1.y * w1.y + a1.z * w1.z + a1.w * w1.w
               + a2.x * w2.x + a2.y * w2.y + a2.z * w2.z + a2.w * w2.w
               + a3.x * w3.x + a3.y * w3.y + a3.z * w3.z + a3.w * w3.w;
    }

#pragma unroll
    for (int r = 0; r < 4; ++r) {
#pragma unroll
        for (int off = 32; off > 0; off >>= 1)
            acc[r] += __shfl_down(acc[r], off, 64);
    }

    if (lane == 0) {
        vfloat4 out = {acc[0], acc[1], acc[2], acc[3]};
        ((vfloat4*)Aw)[row0 >> 2] = out;
    }
}

// ---------------------------------------------------------------------------
// Kernel 2: per bn-tile of 4 rows:
//   Z[r][e] = sum_d X[bn0+r][d] * Aw[d][e]        (phase 1)
//   S[bn0+r][m] = sum_e Z[r][e] * Y[b][m][e] + b  (phase 2)
// 128 blocks x 256 threads; Aw read once per block (4x less traffic than 1/row).
// Phase 2 reads each Y element once per thread, reused across the 4 rows.
// ---------------------------------------------------------------------------
__global__ __launch_bounds__(256) void bilinear_fused_kernel(
    const float* __restrict__ X, const float* __restrict__ Y,
    const float* __restrict__ Aw, const float* __restrict__ bias,
    float* __restrict__ S)
{
    const int bn0 = blockIdx.x * 4;   // 4 consecutive (b,n) rows, same b
    const int b   = bn0 >> 7;
    const int t   = threadIdx.x;

    __shared__ float xs[4][DD];
    __shared__ float zs[4][DD];
    __shared__ float partial[4][256];

#pragma unroll
    for (int r = 0; r < 4; ++r)
        xs[r][t] = X[(size_t)(bn0 + r) * DD + t];
    __syncthreads();

    // Phase 1: e = t; coalesced Aw reads, LDS-broadcast x reads.
    float acc0 = 0.f, acc1 = 0.f, acc2 = 0.f, acc3 = 0.f;
#pragma unroll 4
    for (int d = 0; d < DD; ++d) {
        float aw = Aw[d * DD + t];
        acc0 += xs[0][d] * aw;
        acc1 += xs[1][d] * aw;
        acc2 += xs[2][d] * aw;
        acc3 += xs[3][d] * aw;
    }
    zs[0][t] = acc0; zs[1][t] = acc1; zs[2][t] = acc2; zs[3][t] = acc3;
    __syncthreads();

    // Phase 2: m = t&127, e-half = t>>7. Y read once, reused for 4 rows.
    const int m  = t & 127;
    const int eh = (t >> 7) << 7;   // 0 or 128
    const float4* __restrict__ Y4 = (const float4*)(Y + ((size_t)b * MM + m) * DD + eh);
    const float4* __restrict__ Z0 = (const float4*)(&zs[0][eh]);
    const float4* __restrict__ Z1 = (const float4*)(&zs[1][eh]);
    const float4* __restrict__ Z2 = (const float4*)(&zs[2][eh]);
    const float4* __restrict__ Z3 = (const float4*)(&zs[3][eh]);

    float s0 = 0.f, s1 = 0.f, s2 = 0.f, s3 = 0.f;
#pragma unroll 8
    for (int e = 0; e < 32; ++e) {
        float4 y = Y4[e];
        float4 z;
        z = Z0[e]; s0 += z.x * y.x + z.y * y.y + z.z * y.z + z.w * y.w;
        z = Z1[e]; s1 += z.x * y.x + z.y * y.y + z.z * y.z + z.w * y.w;
        z = Z2[e]; s2 += z.x * y.x + z.y * y.y + z.z * y.z + z.w * y.w;
        z = Z3[e]; s3 += z.x * y.x + z.y * y.y + z.z * y.z + z.w * y.w;
    }
    partial[0][t] = s0; partial[1][t] = s1; partial[2][t] = s2; partial[3][t] = s3;
    __syncthreads();

    if (t < 128) {
        const float b0 = bias[0];
#pragma unroll
        for (int r = 0; r < 4; ++r)
            S[(size_t)(bn0 + r) * MM + t] = partial[r][t] + partial[r][t + 128] + b0;
    }
}

extern "C" void kernel_launch(void* const* d_in, const int* in_sizes, int n_in,
                              void* d_out, int out_size, void* d_ws, size_t ws_size,
                              hipStream_t stream) {
    const float* X    = (const float*)d_in[0];  // [4,128,256]
    const float* Y    = (const float*)d_in[1];  // [4,128,256]
    const float* A    = (const float*)d_in[2];  // [256,256,1024]
    const float* W    = (const float*)d_in[3];  // [1,1024]
    const float* bias = (const float*)d_in[4];  // [1]
    float* S  = (float*)d_out;                  // [4,128,128]
    float* Aw = (float*)d_ws;                   // 65536 floats = 256 KB scratch

    reduce_A_kernel<<<dim3(65536 / 16), dim3(256), 0, stream>>>(A, W, Aw);
    bilinear_fused_kernel<<<dim3(NB * NN / 4), dim3(256), 0, stream>>>(X, Y, Aw, bias, S);
}